// Round 1
// baseline (1315.379 us; speedup 1.0000x reference)
//
#include <hip/hip_runtime.h>
#include <hip/hip_bf16.h>

#define T_ 1024
#define S_ 1024
#define B_ 2
#define H_ 16
#define D_ 64
#define E_ 1024
#define M_ (T_*B_)
#define SCALE_ 0.125f
#define TQ 16
#define TS 64

// ---------------------------------------------------------------------------
// C[m][n] = act((sum_k A[m,k]*W[n,k] + bias[n]) * scale)   (A:MxK, W:NxK, NT)
// 64x64 tile, BK=16, 256 threads, 4x4 micro-tile per thread. fp32.
// ---------------------------------------------------------------------------
template<bool TANH>
__global__ __launch_bounds__(256) void gemm_nt(const float* __restrict__ A,
    const float* __restrict__ W, const float* __restrict__ bias,
    float* __restrict__ C, int M, int N, int K, float scale) {
  __shared__ float sA[16][68];
  __shared__ float sW[16][68];
  const int m0 = blockIdx.y * 64, n0 = blockIdx.x * 64;
  const int tid = threadIdx.x;
  const int tx = tid & 15, ty = tid >> 4;
  const int lrow = tid >> 2;          // 0..63
  const int lkc  = (tid & 3) << 2;    // 0,4,8,12
  float c[4][4] = {};
  for (int k0 = 0; k0 < K; k0 += 16) {
    float4 a4 = *(const float4*)&A[(long)(m0 + lrow) * K + k0 + lkc];
    float4 w4 = *(const float4*)&W[(long)(n0 + lrow) * K + k0 + lkc];
    sA[lkc+0][lrow] = a4.x; sA[lkc+1][lrow] = a4.y;
    sA[lkc+2][lrow] = a4.z; sA[lkc+3][lrow] = a4.w;
    sW[lkc+0][lrow] = w4.x; sW[lkc+1][lrow] = w4.y;
    sW[lkc+2][lrow] = w4.z; sW[lkc+3][lrow] = w4.w;
    __syncthreads();
    #pragma unroll
    for (int kk = 0; kk < 16; ++kk) {
      float4 av = *(const float4*)&sA[kk][ty*4];
      float4 wv = *(const float4*)&sW[kk][tx*4];
      float aa[4] = {av.x,av.y,av.z,av.w};
      float ww[4] = {wv.x,wv.y,wv.z,wv.w};
      #pragma unroll
      for (int i = 0; i < 4; ++i)
        #pragma unroll
        for (int j = 0; j < 4; ++j) c[i][j] += aa[i]*ww[j];
    }
    __syncthreads();
  }
  float4 bv = *(const float4*)&bias[n0 + tx*4];
  float bb[4] = {bv.x,bv.y,bv.z,bv.w};
  #pragma unroll
  for (int i = 0; i < 4; ++i) {
    float r[4];
    #pragma unroll
    for (int j = 0; j < 4; ++j) {
      float val = (c[i][j] + bb[j]) * scale;
      if (TANH) val = tanhf(val);
      r[j] = val;
    }
    *(float4*)&C[(long)(m0+ty*4+i)*N + n0 + tx*4] = *(float4*)r;
  }
}

// ---------------------------------------------------------------------------
// g[m] = sum_e wp[m][e]*Wvp[e] + bvp;  sigma[m] = 1 + sigmoid(g)
// one wave per row m  (wp already has tanh applied by gemm_nt<true>)
// ---------------------------------------------------------------------------
__global__ __launch_bounds__(64) void vp_sigma(const float* __restrict__ wp,
    const float* __restrict__ Wvp, const float* __restrict__ bvp,
    float* __restrict__ sigma) {
  const int m = blockIdx.x;
  const int lane = threadIdx.x;
  float acc = 0.f;
  for (int e = lane*4; e < E_; e += 64*4) {
    float4 a = *(const float4*)&wp[(long)m*E_ + e];
    float4 w = *(const float4*)&Wvp[e];
    acc += a.x*w.x + a.y*w.y + a.z*w.z + a.w*w.w;
  }
  #pragma unroll
  for (int o = 32; o; o >>= 1) acc += __shfl_xor(acc, o);
  if (lane == 0) {
    float g = acc + bvp[0];
    sigma[m] = 1.f + 1.f/(1.f + __expf(-g));
  }
}

// ---------------------------------------------------------------------------
// Fused Gaussian attention. One block = one (bh, 16-query tile).
// pass1: attn logits -> LDS row buffer; online align softmax -> mean
// pass2: content softmax over (attn + gauss)
// pass3: out = P @ V, normalize, store ctx (T,B,E layout)
// ---------------------------------------------------------------------------
__global__ __launch_bounds__(256) void attn_fused(
    const float* __restrict__ q, const float* __restrict__ k,
    const float* __restrict__ v, const float* __restrict__ hq,
    const float* __restrict__ hk, const float* __restrict__ sigma,
    float* __restrict__ ctx) {
  __shared__ float sQ[TQ][D_+4], sHQ[TQ][D_+4];
  __shared__ float sKT[TS][D_+4], sHKT[TS][D_+4];
  __shared__ float sA[TQ][S_];
  __shared__ float sMean[TQ], sFct[TQ], sDen[TQ];

  const int bh = blockIdx.y;
  const int b = bh / H_, h = bh % H_;
  const int t0 = blockIdx.x * TQ;
  const int tid = threadIdx.x;
  const int tt = tid >> 4, ts = tid & 15;

  // load Q / HQ tiles (16x64 each; 256 float4 -> one per thread)
  {
    int qt = tid >> 4;            // 0..15 row
    int dc = (tid & 15) << 2;     // 0..60
    long off = ((long)(t0+qt)*B_ + b)*E_ + h*D_ + dc;
    *(float4*)&sQ[qt][dc]  = *(const float4*)&q[off];
    *(float4*)&sHQ[qt][dc] = *(const float4*)&hq[off];
  }
  __syncthreads();

  float mloc = -1e30f, den = 0.f, num = 0.f;

  for (int s0 = 0; s0 < S_; s0 += TS) {
    // stage K, HK tiles (64x64 each)
    for (int idx = tid; idx < TS*D_/4; idx += 256) {
      int sr = idx >> 4;
      int dc = (idx & 15) << 2;
      long off = ((long)(s0+sr)*B_ + b)*E_ + h*D_ + dc;
      *(float4*)&sKT[sr][dc]  = *(const float4*)&k[off];
      *(float4*)&sHKT[sr][dc] = *(const float4*)&hk[off];
    }
    __syncthreads();

    float a[4] = {0,0,0,0}, z[4] = {0,0,0,0};
    for (int dc = 0; dc < D_; dc += 4) {
      float4 qv = *(const float4*)&sQ[tt][dc];
      float4 hv = *(const float4*)&sHQ[tt][dc];
      #pragma unroll
      for (int j = 0; j < 4; ++j) {
        int sl = ts + j*16;
        float4 kv = *(const float4*)&sKT[sl][dc];
        float4 gv = *(const float4*)&sHKT[sl][dc];
        a[j] += qv.x*kv.x + qv.y*kv.y + qv.z*kv.z + qv.w*kv.w;
        z[j] += hv.x*gv.x + hv.y*gv.y + hv.z*gv.z + hv.w*gv.w;
      }
    }
    #pragma unroll
    for (int j = 0; j < 4; ++j) {
      int s = s0 + ts + j*16;
      sA[tt][s] = a[j];
      float m2 = fmaxf(mloc, z[j]);
      float c0 = __expf(mloc - m2), e0 = __expf(z[j] - m2);
      den = den*c0 + e0;
      num = num*c0 + e0*(float)s;
      mloc = m2;
    }
    __syncthreads();
  }

  // align reduce across the 16 lanes sharing tt
  #pragma unroll
  for (int o = 1; o < 16; o <<= 1) {
    float mo = __shfl_xor(mloc, o);
    float dn = __shfl_xor(den, o);
    float nm = __shfl_xor(num, o);
    float m2 = fmaxf(mloc, mo);
    float c1 = __expf(mloc - m2), c2 = __expf(mo - m2);
    den = den*c1 + dn*c2;
    num = num*c1 + nm*c2;
    mloc = m2;
  }
  if (ts == 0) {
    sMean[tt] = num / den;
    float sg = sigma[(long)(t0+tt)*B_ + b];
    sFct[tt] = -1.f / (2.f*sg*sg);
  }
  __syncthreads();
  const float mean = sMean[tt], fct = sFct[tt];

  // pass 2: content softmax with gaussian bias
  float M2 = -1e30f;
  for (int jj = 0; jj < S_/16; ++jj) {
    int s = ts + jj*16;
    float d = (float)s - mean;
    M2 = fmaxf(M2, sA[tt][s] + d*d*fct);
  }
  #pragma unroll
  for (int o = 1; o < 16; o <<= 1) M2 = fmaxf(M2, __shfl_xor(M2, o));
  float dsum = 0.f;
  for (int jj = 0; jj < S_/16; ++jj) {
    int s = ts + jj*16;
    float d = (float)s - mean;
    float p = __expf(sA[tt][s] + d*d*fct - M2);
    sA[tt][s] = p;
    dsum += p;
  }
  #pragma unroll
  for (int o = 1; o < 16; o <<= 1) dsum += __shfl_xor(dsum, o);
  if (ts == 0) sDen[tt] = dsum;
  __syncthreads();

  // pass 3: out = P @ V   (thread (tt, dd) owns d = dd*4..dd*4+3)
  const int dd = ts;
  float4 out4 = {0.f,0.f,0.f,0.f};
  for (int s0 = 0; s0 < S_; s0 += TS) {
    for (int idx = tid; idx < TS*D_/4; idx += 256) {
      int sr = idx >> 4;
      int dc = (idx & 15) << 2;
      *(float4*)&sKT[sr][dc] =
          *(const float4*)&v[((long)(s0+sr)*B_ + b)*E_ + h*D_ + dc];
    }
    __syncthreads();
    for (int sr = 0; sr < TS; ++sr) {
      float p = sA[tt][s0+sr];
      float4 vv = *(const float4*)&sKT[sr][dd*4];
      out4.x += p*vv.x; out4.y += p*vv.y; out4.z += p*vv.z; out4.w += p*vv.w;
    }
    __syncthreads();
  }
  float inv = 1.f / sDen[tt];
  float4 r;
  r.x = out4.x*inv; r.y = out4.y*inv; r.z = out4.z*inv; r.w = out4.w*inv;
  *(float4*)&ctx[((long)(t0+tt)*B_ + b)*E_ + h*D_ + dd*4] = r;
}

// ---------------------------------------------------------------------------
extern "C" void kernel_launch(void* const* d_in, const int* in_sizes, int n_in,
                              void* d_out, int out_size, void* d_ws, size_t ws_size,
                              hipStream_t stream) {
  const float* query  = (const float*)d_in[0];
  const float* key_in = (const float*)d_in[1];
  const float* value  = (const float*)d_in[2];
  const float* Wq  = (const float*)d_in[3];  const float* bq  = (const float*)d_in[4];
  const float* Wk  = (const float*)d_in[5];  const float* bk  = (const float*)d_in[6];
  const float* Wv  = (const float*)d_in[7];  const float* bv  = (const float*)d_in[8];
  const float* Whq = (const float*)d_in[9];  const float* bhq = (const float*)d_in[10];
  const float* Whk = (const float*)d_in[11]; const float* bhk = (const float*)d_in[12];
  const float* Wwp = (const float*)d_in[13]; const float* bwp = (const float*)d_in[14];
  const float* Wvp = (const float*)d_in[15]; const float* bvp = (const float*)d_in[16];
  const float* Wo  = (const float*)d_in[17]; const float* bo  = (const float*)d_in[18];

  float* ws = (float*)d_ws;
  const size_t SZ = (size_t)M_ * E_;   // 2M floats per buffer
  float* q_   = ws;
  float* k_   = ws + 1*SZ;
  float* v_   = ws + 2*SZ;
  float* hq_  = ws + 3*SZ;
  float* hk_  = ws + 4*SZ;
  float* ctx_ = ws + 5*SZ;             // doubles as wp buffer before attention
  float* sig_ = ws + 6*SZ;             // M_ floats

  dim3 gg(E_/64, M_/64), gb(256);
  // projections
  gemm_nt<false><<<gg, gb, 0, stream>>>(query,  Wq,  bq,  q_,  M_, E_, E_, SCALE_);
  gemm_nt<false><<<gg, gb, 0, stream>>>(key_in, Wk,  bk,  k_,  M_, E_, E_, 1.f);
  gemm_nt<false><<<gg, gb, 0, stream>>>(value,  Wv,  bv,  v_,  M_, E_, E_, 1.f);
  gemm_nt<false><<<gg, gb, 0, stream>>>(query,  Whq, bhq, hq_, M_, E_, E_, SCALE_);
  gemm_nt<false><<<gg, gb, 0, stream>>>(key_in, Whk, bhk, hk_, M_, E_, E_, 1.f);
  gemm_nt<true ><<<gg, gb, 0, stream>>>(query,  Wwp, bwp, ctx_, M_, E_, E_, 1.f);
  // sigma
  vp_sigma<<<dim3(M_), dim3(64), 0, stream>>>(ctx_, Wvp, bvp, sig_);
  // fused gaussian attention  (overwrites ctx_ after wp is consumed)
  attn_fused<<<dim3(T_/TQ, B_*H_), dim3(256), 0, stream>>>(q_, k_, v_, hq_, hk_, sig_, ctx_);
  // output projection
  gemm_nt<false><<<gg, gb, 0, stream>>>(ctx_, Wo, bo, (float*)d_out, M_, E_, E_, 1.f);
}

// Round 2
// 556.974 us; speedup vs baseline: 2.3617x; 2.3617x over previous
//
#include <hip/hip_runtime.h>
#include <hip/hip_bf16.h>

#define T_ 1024
#define S_ 1024
#define B_ 2
#define H_ 16
#define D_ 64
#define E_ 1024
#define M_ (T_*B_)
#define SCALE_ 0.125f

typedef __attribute__((ext_vector_type(8))) short short8;
typedef __attribute__((ext_vector_type(4))) float f32x4;

__device__ __forceinline__ ushort f2bf(float x) {
  unsigned u = __float_as_uint(x);
  unsigned r = (u + 0x7fffu + ((u >> 16) & 1u)) >> 16;
  return (ushort)r;
}
__device__ __forceinline__ float bf2f(ushort h) {
  return __uint_as_float(((unsigned)h) << 16);
}

// ---------------------------------------------------------------------------
// C = act((A @ W^T + bias) * scale).  A: MxK fp32, W: NxK fp32.
// OMODE: 0 = fp32 out (C), 1 = bf16 out (Cb16), 2 = split hi/lo bf16 (Cb16,Clo)
// ---------------------------------------------------------------------------
template<int OMODE, bool TANH>
__global__ __launch_bounds__(256) void gemm_nt(const float* __restrict__ A,
    const float* __restrict__ W, const float* __restrict__ bias,
    float* __restrict__ C, ushort* __restrict__ Cb16, ushort* __restrict__ Clo,
    int M, int N, int K, float scale) {
  __shared__ float sA[16][68];
  __shared__ float sW[16][68];
  const int m0 = blockIdx.y * 64, n0 = blockIdx.x * 64;
  const int tid = threadIdx.x;
  const int tx = tid & 15, ty = tid >> 4;
  const int lrow = tid >> 2;
  const int lkc  = (tid & 3) << 2;
  float c[4][4] = {};
  for (int k0 = 0; k0 < K; k0 += 16) {
    float4 a4 = *(const float4*)&A[(long)(m0 + lrow) * K + k0 + lkc];
    float4 w4 = *(const float4*)&W[(long)(n0 + lrow) * K + k0 + lkc];
    sA[lkc+0][lrow] = a4.x; sA[lkc+1][lrow] = a4.y;
    sA[lkc+2][lrow] = a4.z; sA[lkc+3][lrow] = a4.w;
    sW[lkc+0][lrow] = w4.x; sW[lkc+1][lrow] = w4.y;
    sW[lkc+2][lrow] = w4.z; sW[lkc+3][lrow] = w4.w;
    __syncthreads();
    #pragma unroll
    for (int kk = 0; kk < 16; ++kk) {
      float4 av = *(const float4*)&sA[kk][ty*4];
      float4 wv = *(const float4*)&sW[kk][tx*4];
      float aa[4] = {av.x,av.y,av.z,av.w};
      float ww[4] = {wv.x,wv.y,wv.z,wv.w};
      #pragma unroll
      for (int i = 0; i < 4; ++i)
        #pragma unroll
        for (int j = 0; j < 4; ++j) c[i][j] += aa[i]*ww[j];
    }
    __syncthreads();
  }
  float4 bv = *(const float4*)&bias[n0 + tx*4];
  float bb[4] = {bv.x,bv.y,bv.z,bv.w};
  #pragma unroll
  for (int i = 0; i < 4; ++i) {
    float r[4];
    #pragma unroll
    for (int j = 0; j < 4; ++j) {
      float val = (c[i][j] + bb[j]) * scale;
      if (TANH) val = tanhf(val);
      r[j] = val;
    }
    long off = (long)(m0+ty*4+i)*N + n0 + tx*4;
    if (OMODE == 0) {
      *(float4*)&C[off] = *(float4*)r;
    } else {
      ushort hb[4];
      #pragma unroll
      for (int j = 0; j < 4; ++j) hb[j] = f2bf(r[j]);
      *(ushort4*)&Cb16[off] = make_ushort4(hb[0],hb[1],hb[2],hb[3]);
      if (OMODE == 2) {
        ushort lb[4];
        #pragma unroll
        for (int j = 0; j < 4; ++j) lb[j] = f2bf(r[j] - bf2f(hb[j]));
        *(ushort4*)&Clo[off] = make_ushort4(lb[0],lb[1],lb[2],lb[3]);
      }
    }
  }
}

// ---------------------------------------------------------------------------
// sigma[m] = 1 + sigmoid(sum_e wp[m][e]*Wvp[e] + bvp), one wave per row
// ---------------------------------------------------------------------------
__global__ __launch_bounds__(64) void vp_sigma(const float* __restrict__ wp,
    const float* __restrict__ Wvp, const float* __restrict__ bvp,
    float* __restrict__ sigma) {
  const int m = blockIdx.x;
  const int lane = threadIdx.x;
  float acc = 0.f;
  for (int e = lane*4; e < E_; e += 64*4) {
    float4 a = *(const float4*)&wp[(long)m*E_ + e];
    float4 w = *(const float4*)&Wvp[e];
    acc += a.x*w.x + a.y*w.y + a.z*w.z + a.w*w.w;
  }
  #pragma unroll
  for (int o = 32; o; o >>= 1) acc += __shfl_xor(acc, o);
  if (lane == 0) {
    float g = acc + bvp[0];
    sigma[m] = 1.f + 1.f/(1.f + __expf(-g));
  }
}

// ---------------------------------------------------------------------------
// MFMA flash attention with Gaussian bias.
// Block = one (b,h) x 64 queries; 4 waves x 16 q each; S-tiles of 64.
// Pass1: align logits via split-bf16 (hi*hi + hi*lo + lo*hi) -> online mean.
// Pass2: content logits bf16 + gauss -> online softmax -> PV (bf16 MFMA).
// mfma_f32_16x16x32_bf16, swapped operands: mfma(K_tile, Q^T) -> L^T so the
// per-q softmax state is lane-indexed (col = lane&15).
// ---------------------------------------------------------------------------
__global__ __launch_bounds__(256) void attn_mfma(
    const ushort* __restrict__ q_bf, const ushort* __restrict__ k_bf,
    const ushort* __restrict__ v_bf,
    const ushort* __restrict__ hq_hi, const ushort* __restrict__ hq_lo,
    const ushort* __restrict__ hk_hi, const ushort* __restrict__ hk_lo,
    const float* __restrict__ sigma, float* __restrict__ ctx) {
  __shared__ ushort sA[64][72];      // K tile or HK_hi tile, [s][d], pad->72
  __shared__ ushort sB[64][72];      // V^T tile [d][s] or HK_lo tile [s][d]
  __shared__ ushort sP[4][16][72];   // per-wave P[q][s] bf16

  const int bh = blockIdx.y;
  const int b = bh >> 4, h = bh & 15;
  const int t0 = blockIdx.x * 64;
  const int tid = threadIdx.x;
  const int wv = tid >> 6, lane = tid & 63;
  const int c = lane & 15, g = lane >> 4;
  const int qbase = t0 + wv * 16;                  // wave's q rows

  const long rowstr = (long)B_ * E_;
  const long qoff = ((long)(qbase + c) * B_ + b) * E_ + h * 64;

  // resident B-fragments: element k = 32*cs + 8*g + j  (row/col = lane&15)
  short8 qf[2], hqh[2], hql[2];
  #pragma unroll
  for (int cs = 0; cs < 2; ++cs) {
    qf[cs]  = *(const short8*)&q_bf [qoff + cs*32 + g*8];
    hqh[cs] = *(const short8*)&hq_hi[qoff + cs*32 + g*8];
    hql[cs] = *(const short8*)&hq_lo[qoff + cs*32 + g*8];
  }

  // ------------------- pass 1: alignment softmax -> mean -------------------
  float mloc = -1e30f, den = 0.f, num = 0.f;
  for (int s0 = 0; s0 < S_; s0 += 64) {
    __syncthreads();
    #pragma unroll
    for (int it = 0; it < 2; ++it) {
      int i = tid + it*256;
      int sr = i >> 3, dc = (i & 7) * 8;
      long off = ((long)(s0 + sr) * B_ + b) * E_ + h * 64 + dc;
      *(uint4*)&sA[sr][dc] = *(const uint4*)&hk_hi[off];
      *(uint4*)&sB[sr][dc] = *(const uint4*)&hk_lo[off];
    }
    __syncthreads();
    f32x4 acc[4] = {};
    #pragma unroll
    for (int m = 0; m < 4; ++m) {
      #pragma unroll
      for (int cs = 0; cs < 2; ++cs) {
        short8 khi = *(const short8*)&sA[c + 16*m][cs*32 + g*8];
        short8 klo = *(const short8*)&sB[c + 16*m][cs*32 + g*8];
        acc[m] = __builtin_amdgcn_mfma_f32_16x16x32_bf16(khi, hqh[cs], acc[m], 0,0,0);
        acc[m] = __builtin_amdgcn_mfma_f32_16x16x32_bf16(khi, hql[cs], acc[m], 0,0,0);
        acc[m] = __builtin_amdgcn_mfma_f32_16x16x32_bf16(klo, hqh[cs], acc[m], 0,0,0);
      }
    }
    #pragma unroll
    for (int m = 0; m < 4; ++m)
      #pragma unroll
      for (int r = 0; r < 4; ++r) {
        float z = acc[m][r];
        float sp = (float)(s0 + 16*m + 4*g + r);
        float m2 = fmaxf(mloc, z);
        float sc = __expf(mloc - m2), e0 = __expf(z - m2);
        den = den * sc + e0;
        num = num * sc + e0 * sp;
        mloc = m2;
      }
  }
  #pragma unroll
  for (int o = 16; o < 64; o <<= 1) {
    float mo = __shfl_xor(mloc, o);
    float dn = __shfl_xor(den, o);
    float nm = __shfl_xor(num, o);
    float m2 = fmaxf(mloc, mo);
    float c1 = __expf(mloc - m2), c2 = __expf(mo - m2);
    den = den*c1 + dn*c2;
    num = num*c1 + nm*c2;
    mloc = m2;
  }
  const float meanq = num / den;                  // q = qbase + c
  const float sg = sigma[(long)(qbase + c) * B_ + b];
  const float fct = -1.f / (2.f * sg * sg);

  // ------------------- pass 2: content softmax + PV -------------------------
  f32x4 accO[4] = {};                             // O[q=4g+r][d=16n+c]
  float Mq = -1e30f, denq = 0.f;                  // per q = qbase + c
  for (int s0 = 0; s0 < S_; s0 += 64) {
    __syncthreads();
    #pragma unroll
    for (int it = 0; it < 2; ++it) {              // stage K [s][d]
      int i = tid + it*256;
      int sr = i >> 3, dc = (i & 7) * 8;
      long off = ((long)(s0 + sr) * B_ + b) * E_ + h * 64 + dc;
      *(uint4*)&sA[sr][dc] = *(const uint4*)&k_bf[off];
    }
    {                                             // stage V^T [d][s]
      int s2 = (tid & 31) * 2, d0 = (tid >> 5) * 8;
      long off0 = ((long)(s0 + s2) * B_ + b) * E_ + h * 64 + d0;
      uint4 ra = *(const uint4*)&v_bf[off0];
      uint4 rb = *(const uint4*)&v_bf[off0 + rowstr];
      const ushort* pa = (const ushort*)&ra;
      const ushort* pb = (const ushort*)&rb;
      #pragma unroll
      for (int j = 0; j < 8; ++j)
        *(unsigned*)&sB[d0 + j][s2] = (unsigned)pa[j] | ((unsigned)pb[j] << 16);
    }
    __syncthreads();

    f32x4 accL[4] = {};
    #pragma unroll
    for (int m = 0; m < 4; ++m)
      #pragma unroll
      for (int cs = 0; cs < 2; ++cs)
        accL[m] = __builtin_amdgcn_mfma_f32_16x16x32_bf16(
            *(const short8*)&sA[c + 16*m][cs*32 + g*8], qf[cs], accL[m], 0,0,0);

    float lg[4][4];
    float lmax = -1e30f;
    #pragma unroll
    for (int m = 0; m < 4; ++m)
      #pragma unroll
      for (int r = 0; r < 4; ++r) {
        float sp = (float)(s0 + 16*m + 4*g + r);
        float dd = sp - meanq;
        float l = accL[m][r] + fct * dd * dd;
        lg[m][r] = l;
        lmax = fmaxf(lmax, l);
      }
    lmax = fmaxf(lmax, __shfl_xor(lmax, 16));
    lmax = fmaxf(lmax, __shfl_xor(lmax, 32));
    float Mnew = fmaxf(Mq, lmax);
    float c0 = __expf(Mq - Mnew);
    float psum = 0.f;
    ushort pb16[4][4];
    #pragma unroll
    for (int m = 0; m < 4; ++m)
      #pragma unroll
      for (int r = 0; r < 4; ++r) {
        float p = __expf(lg[m][r] - Mnew);
        psum += p;
        pb16[m][r] = f2bf(p);
      }
    denq = denq * c0 + psum;
    Mq = Mnew;
    #pragma unroll
    for (int m = 0; m < 4; ++m)
      *(ushort4*)&sP[wv][c][16*m + 4*g] =
          make_ushort4(pb16[m][0], pb16[m][1], pb16[m][2], pb16[m][3]);

    float c0r[4];
    #pragma unroll
    for (int r = 0; r < 4; ++r) c0r[r] = __shfl(c0, 4*g + r);
    #pragma unroll
    for (int n = 0; n < 4; ++n)
      #pragma unroll
      for (int r = 0; r < 4; ++r) accO[n][r] *= c0r[r];

    #pragma unroll
    for (int n = 0; n < 4; ++n)
      #pragma unroll
      for (int cs = 0; cs < 2; ++cs)
        accO[n] = __builtin_amdgcn_mfma_f32_16x16x32_bf16(
            *(const short8*)&sP[wv][c][cs*32 + 8*g],     // A = P[q][s]
            *(const short8*)&sB[c + 16*n][cs*32 + 8*g],  // B = V^T[d][s]
            accO[n], 0,0,0);
  }

  denq += __shfl_xor(denq, 16);
  denq += __shfl_xor(denq, 32);
  float dinv[4];
  #pragma unroll
  for (int r = 0; r < 4; ++r) dinv[r] = 1.f / __shfl(denq, 4*g + r);

  #pragma unroll
  for (int r = 0; r < 4; ++r) {
    long row = ((long)(t0 + wv*16 + 4*g + r) * B_ + b) * E_ + h * 64;
    #pragma unroll
    for (int n = 0; n < 4; ++n)
      ctx[row + 16*n + c] = accO[n][r] * dinv[r];
  }
}

// ---------------------------------------------------------------------------
extern "C" void kernel_launch(void* const* d_in, const int* in_sizes, int n_in,
                              void* d_out, int out_size, void* d_ws, size_t ws_size,
                              hipStream_t stream) {
  const float* query  = (const float*)d_in[0];
  const float* key_in = (const float*)d_in[1];
  const float* value  = (const float*)d_in[2];
  const float* Wq  = (const float*)d_in[3];  const float* bq  = (const float*)d_in[4];
  const float* Wk  = (const float*)d_in[5];  const float* bk  = (const float*)d_in[6];
  const float* Wv  = (const float*)d_in[7];  const float* bv  = (const float*)d_in[8];
  const float* Whq = (const float*)d_in[9];  const float* bhq = (const float*)d_in[10];
  const float* Whk = (const float*)d_in[11]; const float* bhk = (const float*)d_in[12];
  const float* Wwp = (const float*)d_in[13]; const float* bwp = (const float*)d_in[14];
  const float* Wvp = (const float*)d_in[15]; const float* bvp = (const float*)d_in[16];
  const float* Wo  = (const float*)d_in[17]; const float* bo  = (const float*)d_in[18];

  const size_t NF = (size_t)M_ * E_;     // elements per activation
  char* p = (char*)d_ws;
  float* ctx_ = (float*)p;  p += NF * 4;
  float* wp_  = (float*)p;  p += NF * 4;
  float* sig_ = (float*)p;  p += 16384;
  ushort* q_bf   = (ushort*)p; p += NF * 2;
  ushort* k_bf   = (ushort*)p; p += NF * 2;
  ushort* v_bf   = (ushort*)p; p += NF * 2;
  ushort* hq_hi  = (ushort*)p; p += NF * 2;
  ushort* hq_lo  = (ushort*)p; p += NF * 2;
  ushort* hk_hi  = (ushort*)p; p += NF * 2;
  ushort* hk_lo  = (ushort*)p; p += NF * 2;

  dim3 gg(E_/64, M_/64), gb(256);
  gemm_nt<1,false><<<gg, gb, 0, stream>>>(query,  Wq,  bq,  nullptr, q_bf, nullptr, M_, E_, E_, SCALE_);
  gemm_nt<1,false><<<gg, gb, 0, stream>>>(key_in, Wk,  bk,  nullptr, k_bf, nullptr, M_, E_, E_, 1.f);
  gemm_nt<1,false><<<gg, gb, 0, stream>>>(value,  Wv,  bv,  nullptr, v_bf, nullptr, M_, E_, E_, 1.f);
  gemm_nt<2,false><<<gg, gb, 0, stream>>>(query,  Whq, bhq, nullptr, hq_hi, hq_lo, M_, E_, E_, SCALE_);
  gemm_nt<2,false><<<gg, gb, 0, stream>>>(key_in, Whk, bhk, nullptr, hk_hi, hk_lo, M_, E_, E_, 1.f);
  gemm_nt<0,true ><<<gg, gb, 0, stream>>>(query,  Wwp, bwp, wp_, nullptr, nullptr, M_, E_, E_, 1.f);
  vp_sigma<<<dim3(M_), dim3(64), 0, stream>>>(wp_, Wvp, bvp, sig_);
  attn_mfma<<<dim3(T_/64, B_*H_), dim3(256), 0, stream>>>(
      q_bf, k_bf, v_bf, hq_hi, hq_lo, hk_hi, hk_lo, sig_, ctx_);
  gemm_nt<0,false><<<gg, gb, 0, stream>>>(ctx_, Wo, bo, (float*)d_out, nullptr, nullptr, M_, E_, E_, 1.f);
}

// Round 3
// 195.325 us; speedup vs baseline: 6.7343x; 2.8515x over previous
//
#include <hip/hip_runtime.h>
#include <hip/hip_bf16.h>

#define T_ 1024
#define S_ 1024
#define B_ 2
#define H_ 16
#define D_ 64
#define E_ 1024
#define M_ (T_*B_)
#define SCALE_ 0.125f

typedef __attribute__((ext_vector_type(8))) short short8;
typedef __attribute__((ext_vector_type(4))) float f32x4;

__device__ __forceinline__ ushort f2bf(float x) {
  unsigned u = __float_as_uint(x);
  unsigned r = (u + 0x7fffu + ((u >> 16) & 1u)) >> 16;
  return (ushort)r;
}
__device__ __forceinline__ float bf2f(ushort h) {
  return __uint_as_float(((unsigned)h) << 16);
}
__device__ __forceinline__ void gld16(const void* g, void* l) {
  __builtin_amdgcn_global_load_lds(
      (const __attribute__((address_space(1))) void*)g,
      (__attribute__((address_space(3))) void*)l, 16, 0, 0);
}

// ---------------------------------------------------------------------------
// fp32 -> bf16 (hi) and optional residual (lo) conversion, multi-tensor
// ---------------------------------------------------------------------------
struct CvtDesc { const float* src; ushort* hi; ushort* lo; int n4; };
struct CvtArgs { CvtDesc d[8]; };

__global__ __launch_bounds__(256) void cvt_kernel(CvtArgs a) {
  const CvtDesc d = a.d[blockIdx.y];
  const int stride = gridDim.x * 256;
  for (int i = blockIdx.x*256 + threadIdx.x; i < d.n4; i += stride) {
    float4 v = ((const float4*)d.src)[i];
    float vals[4] = {v.x, v.y, v.z, v.w};
    ushort h[4];
    #pragma unroll
    for (int j = 0; j < 4; ++j) h[j] = f2bf(vals[j]);
    ((ushort4*)d.hi)[i] = make_ushort4(h[0],h[1],h[2],h[3]);
    if (d.lo) {
      ushort l[4];
      #pragma unroll
      for (int j = 0; j < 4; ++j) l[j] = f2bf(vals[j] - bf2f(h[j]));
      ((ushort4*)d.lo)[i] = make_ushort4(l[0],l[1],l[2],l[3]);
    }
  }
}

// ---------------------------------------------------------------------------
// Plain bf16 MFMA GEMM: C_seg = act((A @ W^T + bias) * scale)
// Tile 128(M) x 64(N), BK=64, 4 waves (2Mx2N), 16 blocks-x per segment.
// A: 2048xK bf16 row-major, W: 1024xK bf16 row-major (K=1024).
// ---------------------------------------------------------------------------
struct SegP { const ushort* A; const ushort* W; const float* bias;
              ushort* outb; float* outf; float scale; int do_tanh; };
struct PlainArgs { SegP s[4]; };

__global__ __launch_bounds__(256) void gemm_mfma_plain(PlainArgs args) {
  __shared__ ushort sA[128*64];
  __shared__ ushort sW[64*64];
  const int bx = blockIdx.x;
  const SegP sg = args.s[bx >> 4];
  const int n0 = (bx & 15) * 64;
  const int m0 = blockIdx.y * 128;
  const int tid = threadIdx.x, wv = tid >> 6, lane = tid & 63;
  const int c = lane & 15, g = lane >> 4;
  const int wr = wv >> 1, wc = wv & 1;
  const int l8 = lane >> 3, l7 = lane & 7;

  f32x4 acc[4][2] = {};
  for (int k0 = 0; k0 < 1024; k0 += 64) {
    #pragma unroll
    for (int i = 0; i < 4; ++i) {
      int row = wv*32 + i*8 + l8;
      gld16(sg.A + (size_t)(m0+row)*1024 + k0 + l7*8, &sA[(wv*32 + i*8)*64]);
    }
    #pragma unroll
    for (int i = 0; i < 2; ++i) {
      int row = wv*16 + i*8 + l8;
      gld16(sg.W + (size_t)(n0+row)*1024 + k0 + l7*8, &sW[(wv*16 + i*8)*64]);
    }
    __syncthreads();
    #pragma unroll
    for (int ks = 0; ks < 2; ++ks) {
      short8 af[4], wf[2];
      #pragma unroll
      for (int mi = 0; mi < 4; ++mi)
        af[mi] = *(const short8*)&sA[(wr*64 + mi*16 + c)*64 + ks*32 + g*8];
      #pragma unroll
      for (int ni = 0; ni < 2; ++ni)
        wf[ni] = *(const short8*)&sW[(wc*32 + ni*16 + c)*64 + ks*32 + g*8];
      #pragma unroll
      for (int mi = 0; mi < 4; ++mi)
        #pragma unroll
        for (int ni = 0; ni < 2; ++ni)
          acc[mi][ni] = __builtin_amdgcn_mfma_f32_16x16x32_bf16(
              af[mi], wf[ni], acc[mi][ni], 0, 0, 0);
    }
    __syncthreads();
  }
  #pragma unroll
  for (int ni = 0; ni < 2; ++ni) {
    int col = n0 + wc*32 + ni*16 + c;
    float bias = sg.bias[col];
    #pragma unroll
    for (int mi = 0; mi < 4; ++mi) {
      #pragma unroll
      for (int r = 0; r < 4; ++r) {
        int row = m0 + wr*64 + mi*16 + 4*g + r;
        float val = (acc[mi][ni][r] + bias) * sg.scale;
        if (sg.do_tanh) val = tanhf(val);
        if (sg.outf) sg.outf[(size_t)row*1024 + col] = val;
        else         sg.outb[(size_t)row*1024 + col] = f2bf(val);
      }
    }
  }
}

// ---------------------------------------------------------------------------
// Split-precision MFMA GEMM (hi/lo bf16 inputs, ~fp32 result):
// C = Ah.Wh + Ah.Wl + Al.Wh; epilogue emits hi/lo bf16 pair.
// ---------------------------------------------------------------------------
struct SegS { const ushort *Ah, *Al, *Wh, *Wl; const float* bias;
              ushort *oh, *ol; float scale; };
struct SplitArgs { SegS s[2]; };

__global__ __launch_bounds__(256) void gemm_mfma_split(SplitArgs args) {
  __shared__ ushort sAh[128*64], sAl[128*64];
  __shared__ ushort sWh[64*64],  sWl[64*64];
  const int bx = blockIdx.x;
  const SegS sg = args.s[bx >> 4];
  const int n0 = (bx & 15) * 64;
  const int m0 = blockIdx.y * 128;
  const int tid = threadIdx.x, wv = tid >> 6, lane = tid & 63;
  const int c = lane & 15, g = lane >> 4;
  const int wr = wv >> 1, wc = wv & 1;
  const int l8 = lane >> 3, l7 = lane & 7;

  f32x4 acc[4][2] = {};
  for (int k0 = 0; k0 < 1024; k0 += 64) {
    #pragma unroll
    for (int i = 0; i < 4; ++i) {
      int row = wv*32 + i*8 + l8;
      size_t go = (size_t)(m0+row)*1024 + k0 + l7*8;
      gld16(sg.Ah + go, &sAh[(wv*32 + i*8)*64]);
      gld16(sg.Al + go, &sAl[(wv*32 + i*8)*64]);
    }
    #pragma unroll
    for (int i = 0; i < 2; ++i) {
      int row = wv*16 + i*8 + l8;
      size_t go = (size_t)(n0+row)*1024 + k0 + l7*8;
      gld16(sg.Wh + go, &sWh[(wv*16 + i*8)*64]);
      gld16(sg.Wl + go, &sWl[(wv*16 + i*8)*64]);
    }
    __syncthreads();
    #pragma unroll
    for (int ks = 0; ks < 2; ++ks) {
      short8 ah[4], al[4], wh[2], wl[2];
      #pragma unroll
      for (int mi = 0; mi < 4; ++mi) {
        int off = (wr*64 + mi*16 + c)*64 + ks*32 + g*8;
        ah[mi] = *(const short8*)&sAh[off];
        al[mi] = *(const short8*)&sAl[off];
      }
      #pragma unroll
      for (int ni = 0; ni < 2; ++ni) {
        int off = (wc*32 + ni*16 + c)*64 + ks*32 + g*8;
        wh[ni] = *(const short8*)&sWh[off];
        wl[ni] = *(const short8*)&sWl[off];
      }
      #pragma unroll
      for (int mi = 0; mi < 4; ++mi)
        #pragma unroll
        for (int ni = 0; ni < 2; ++ni) {
          acc[mi][ni] = __builtin_amdgcn_mfma_f32_16x16x32_bf16(
              al[mi], wh[ni], acc[mi][ni], 0, 0, 0);
          acc[mi][ni] = __builtin_amdgcn_mfma_f32_16x16x32_bf16(
              ah[mi], wl[ni], acc[mi][ni], 0, 0, 0);
          acc[mi][ni] = __builtin_amdgcn_mfma_f32_16x16x32_bf16(
              ah[mi], wh[ni], acc[mi][ni], 0, 0, 0);
        }
    }
    __syncthreads();
  }
  #pragma unroll
  for (int ni = 0; ni < 2; ++ni) {
    int col = n0 + wc*32 + ni*16 + c;
    float bias = sg.bias[col];
    #pragma unroll
    for (int mi = 0; mi < 4; ++mi) {
      #pragma unroll
      for (int r = 0; r < 4; ++r) {
        int row = m0 + wr*64 + mi*16 + 4*g + r;
        float val = (acc[mi][ni][r] + bias) * sg.scale;
        ushort hb = f2bf(val);
        sg.oh[(size_t)row*1024 + col] = hb;
        sg.ol[(size_t)row*1024 + col] = f2bf(val - bf2f(hb));
      }
    }
  }
}

// ---------------------------------------------------------------------------
// sigma[m] = 1 + sigmoid(sum_e wp_bf[m][e]*Wvp[e] + bvp), one wave per row
// ---------------------------------------------------------------------------
__global__ __launch_bounds__(64) void vp_sigma(const ushort* __restrict__ wp,
    const float* __restrict__ Wvp, const float* __restrict__ bvp,
    float* __restrict__ sigma) {
  const int m = blockIdx.x;
  const int lane = threadIdx.x;
  float acc = 0.f;
  #pragma unroll
  for (int it = 0; it < 2; ++it) {
    int e = lane*8 + it*512;
    short8 a = *(const short8*)&wp[(size_t)m*E_ + e];
    float4 w0 = *(const float4*)&Wvp[e];
    float4 w1 = *(const float4*)&Wvp[e+4];
    acc += bf2f((ushort)a[0])*w0.x + bf2f((ushort)a[1])*w0.y
         + bf2f((ushort)a[2])*w0.z + bf2f((ushort)a[3])*w0.w
         + bf2f((ushort)a[4])*w1.x + bf2f((ushort)a[5])*w1.y
         + bf2f((ushort)a[6])*w1.z + bf2f((ushort)a[7])*w1.w;
  }
  #pragma unroll
  for (int o = 32; o; o >>= 1) acc += __shfl_xor(acc, o);
  if (lane == 0) {
    float gg = acc + bvp[0];
    sigma[m] = 1.f + 1.f/(1.f + __expf(-gg));
  }
}

// ---------------------------------------------------------------------------
// MFMA flash attention with Gaussian bias (unchanged from round 2 except the
// context output is now bf16).
// ---------------------------------------------------------------------------
__global__ __launch_bounds__(256) void attn_mfma(
    const ushort* __restrict__ q_bf, const ushort* __restrict__ k_bf,
    const ushort* __restrict__ v_bf,
    const ushort* __restrict__ hq_hi, const ushort* __restrict__ hq_lo,
    const ushort* __restrict__ hk_hi, const ushort* __restrict__ hk_lo,
    const float* __restrict__ sigma, ushort* __restrict__ ctx) {
  __shared__ ushort sA[64][72];
  __shared__ ushort sB[64][72];
  __shared__ ushort sP[4][16][72];

  const int bh = blockIdx.y;
  const int b = bh >> 4, h = bh & 15;
  const int t0 = blockIdx.x * 64;
  const int tid = threadIdx.x;
  const int wv = tid >> 6, lane = tid & 63;
  const int c = lane & 15, g = lane >> 4;
  const int qbase = t0 + wv * 16;

  const long rowstr = (long)B_ * E_;
  const long qoff = ((long)(qbase + c) * B_ + b) * E_ + h * 64;

  short8 qf[2], hqh[2], hql[2];
  #pragma unroll
  for (int cs = 0; cs < 2; ++cs) {
    qf[cs]  = *(const short8*)&q_bf [qoff + cs*32 + g*8];
    hqh[cs] = *(const short8*)&hq_hi[qoff + cs*32 + g*8];
    hql[cs] = *(const short8*)&hq_lo[qoff + cs*32 + g*8];
  }

  float mloc = -1e30f, den = 0.f, num = 0.f;
  for (int s0 = 0; s0 < S_; s0 += 64) {
    __syncthreads();
    #pragma unroll
    for (int it = 0; it < 2; ++it) {
      int i = tid + it*256;
      int sr = i >> 3, dc = (i & 7) * 8;
      long off = ((long)(s0 + sr) * B_ + b) * E_ + h * 64 + dc;
      *(uint4*)&sA[sr][dc] = *(const uint4*)&hk_hi[off];
      *(uint4*)&sB[sr][dc] = *(const uint4*)&hk_lo[off];
    }
    __syncthreads();
    f32x4 acc[4] = {};
    #pragma unroll
    for (int m = 0; m < 4; ++m) {
      #pragma unroll
      for (int cs = 0; cs < 2; ++cs) {
        short8 khi = *(const short8*)&sA[c + 16*m][cs*32 + g*8];
        short8 klo = *(const short8*)&sB[c + 16*m][cs*32 + g*8];
        acc[m] = __builtin_amdgcn_mfma_f32_16x16x32_bf16(khi, hqh[cs], acc[m], 0,0,0);
        acc[m] = __builtin_amdgcn_mfma_f32_16x16x32_bf16(khi, hql[cs], acc[m], 0,0,0);
        acc[m] = __builtin_amdgcn_mfma_f32_16x16x32_bf16(klo, hqh[cs], acc[m], 0,0,0);
      }
    }
    #pragma unroll
    for (int m = 0; m < 4; ++m)
      #pragma unroll
      for (int r = 0; r < 4; ++r) {
        float z = acc[m][r];
        float sp = (float)(s0 + 16*m + 4*g + r);
        float m2 = fmaxf(mloc, z);
        float sc = __expf(mloc - m2), e0 = __expf(z - m2);
        den = den * sc + e0;
        num = num * sc + e0 * sp;
        mloc = m2;
      }
  }
  #pragma unroll
  for (int o = 16; o < 64; o <<= 1) {
    float mo = __shfl_xor(mloc, o);
    float dn = __shfl_xor(den, o);
    float nm = __shfl_xor(num, o);
    float m2 = fmaxf(mloc, mo);
    float c1 = __expf(mloc - m2), c2 = __expf(mo - m2);
    den = den*c1 + dn*c2;
    num = num*c1 + nm*c2;
    mloc = m2;
  }
  const float meanq = num / den;
  const float sg = sigma[(long)(qbase + c) * B_ + b];
  const float fct = -1.f / (2.f * sg * sg);

  f32x4 accO[4] = {};
  float Mq = -1e30f, denq = 0.f;
  for (int s0 = 0; s0 < S_; s0 += 64) {
    __syncthreads();
    #pragma unroll
    for (int it = 0; it < 2; ++it) {
      int i = tid + it*256;
      int sr = i >> 3, dc = (i & 7) * 8;
      long off = ((long)(s0 + sr) * B_ + b) * E_ + h * 64 + dc;
      *(uint4*)&sA[sr][dc] = *(const uint4*)&k_bf[off];
    }
    {
      int s2 = (tid & 31) * 2, d0 = (tid >> 5) * 8;
      long off0 = ((long)(s0 + s2) * B_ + b) * E_ + h * 64 + d0;
      uint4 ra = *(const uint4*)&v_bf[off0];
      uint4 rb = *(const uint4*)&v_bf[off0 + rowstr];
      const ushort* pa = (const ushort*)&ra;
      const ushort* pb = (const ushort*)&rb;
      #pragma unroll
      for (int j = 0; j < 8; ++j)
        *(unsigned*)&sB[d0 + j][s2] = (unsigned)pa[j] | ((unsigned)pb[j] << 16);
    }
    __syncthreads();

    f32x4 accL[4] = {};
    #pragma unroll
    for (int m = 0; m < 4; ++m)
      #pragma unroll
      for (int cs = 0; cs < 2; ++cs)
        accL[m] = __builtin_amdgcn_mfma_f32_16x16x32_bf16(
            *(const short8*)&sA[c + 16*m][cs*32 + g*8], qf[cs], accL[m], 0,0,0);

    float lg[4][4];
    float lmax = -1e30f;
    #pragma unroll
    for (int m = 0; m < 4; ++m)
      #pragma unroll
      for (int r = 0; r < 4; ++r) {
        float sp = (float)(s0 + 16*m + 4*g + r);
        float dd = sp - meanq;
        float l = accL[m][r] + fct * dd * dd;
        lg[m][r] = l;
        lmax = fmaxf(lmax, l);
      }
    lmax = fmaxf(lmax, __shfl_xor(lmax, 16));
    lmax = fmaxf(lmax, __shfl_xor(lmax, 32));
    float Mnew = fmaxf(Mq, lmax);
    float c0 = __expf(Mq - Mnew);
    float psum = 0.f;
    ushort pb16[4][4];
    #pragma unroll
    for (int m = 0; m < 4; ++m)
      #pragma unroll
      for (int r = 0; r < 4; ++r) {
        float p = __expf(lg[m][r] - Mnew);
        psum += p;
        pb16[m][r] = f2bf(p);
      }
    denq = denq * c0 + psum;
    Mq = Mnew;
    #pragma unroll
    for (int m = 0; m < 4; ++m)
      *(ushort4*)&sP[wv][c][16*m + 4*g] =
          make_ushort4(pb16[m][0], pb16[m][1], pb16[m][2], pb16[m][3]);

    float c0r[4];
    #pragma unroll
    for (int r = 0; r < 4; ++r) c0r[r] = __shfl(c0, 4*g + r);
    #pragma unroll
    for (int n = 0; n < 4; ++n)
      #pragma unroll
      for (int r = 0; r < 4; ++r) accO[n][r] *= c0r[r];

    #pragma unroll
    for (int n = 0; n < 4; ++n)
      #pragma unroll
      for (int cs = 0; cs < 2; ++cs)
        accO[n] = __builtin_amdgcn_mfma_f32_16x16x32_bf16(
            *(const short8*)&sP[wv][c][cs*32 + 8*g],
            *(const short8*)&sB[c + 16*n][cs*32 + 8*g],
            accO[n], 0,0,0);
  }

  denq += __shfl_xor(denq, 16);
  denq += __shfl_xor(denq, 32);
  float dinv[4];
  #pragma unroll
  for (int r = 0; r < 4; ++r) dinv[r] = 1.f / __shfl(denq, 4*g + r);

  #pragma unroll
  for (int r = 0; r < 4; ++r) {
    long row = ((long)(t0 + wv*16 + 4*g + r) * B_ + b) * E_ + h * 64;
    #pragma unroll
    for (int n = 0; n < 4; ++n)
      ctx[row + 16*n + c] = f2bf(accO[n][r] * dinv[r]);
  }
}

// ---------------------------------------------------------------------------
extern "C" void kernel_launch(void* const* d_in, const int* in_sizes, int n_in,
                              void* d_out, int out_size, void* d_ws, size_t ws_size,
                              hipStream_t stream) {
  const float* query  = (const float*)d_in[0];
  const float* key_in = (const float*)d_in[1];
  const float* value  = (const float*)d_in[2];
  const float* Wq  = (const float*)d_in[3];  const float* bq  = (const float*)d_in[4];
  const float* Wk  = (const float*)d_in[5];  const float* bk  = (const float*)d_in[6];
  const float* Wv  = (const float*)d_in[7];  const float* bv  = (const float*)d_in[8];
  const float* Whq = (const float*)d_in[9];  const float* bhq = (const float*)d_in[10];
  const float* Whk = (const float*)d_in[11]; const float* bhk = (const float*)d_in[12];
  const float* Wwp = (const float*)d_in[13]; const float* bwp = (const float*)d_in[14];
  const float* Wvp = (const float*)d_in[15]; const float* bvp = (const float*)d_in[16];
  const float* Wo  = (const float*)d_in[17]; const float* bo  = (const float*)d_in[18];

  const size_t AU = (size_t)M_ * E_;       // 2M elems (4 MB as bf16)
  const size_t WU = (size_t)E_ * E_;       // 1M elems (2 MB as bf16)
  char* p = (char*)d_ws;
  float*  sig      = (float*)p;  p += 16384;
  ushort* query_hi = (ushort*)p; p += AU*2;   // u0
  ushort* query_lo = (ushort*)p; p += AU*2;   // u1 -> value_bf after P2
  ushort* key_hi   = (ushort*)p; p += AU*2;   // u2
  ushort* key_lo   = (ushort*)p; p += AU*2;   // u3 -> ctx_bf after P2
  ushort* hq_hi    = (ushort*)p; p += AU*2;   // u4
  ushort* hq_lo    = (ushort*)p; p += AU*2;   // u5
  ushort* hk_hi    = (ushort*)p; p += AU*2;   // u6
  ushort* hk_lo    = (ushort*)p; p += AU*2;   // u7
  ushort* u8       = (ushort*)p; p += AU*2;   // Whq_hi|Whk_hi -> q_bf
  ushort* u9       = (ushort*)p; p += AU*2;   // Whq_lo|Whk_lo -> k_bf
  ushort* u10      = (ushort*)p; p += AU*2;   // Wq|Wk -> Wo after P1
  ushort* u11      = (ushort*)p; p += AU*2;   // Wv|Wwp
  ushort* wp_bf    = (ushort*)p; p += AU*2;   // u12
  ushort* v_out    = (ushort*)p; p += AU*2;   // u13
  ushort* value_bf = query_lo;
  ushort* ctx_bf   = key_lo;
  ushort* q_bf = u8, *k_bf = u9;
  ushort* Whq_hi = u8,        *Whk_hi = u8 + WU;
  ushort* Whq_lo = u9,        *Whk_lo = u9 + WU;
  ushort* Wq_bf  = u10,       *Wk_bf  = u10 + WU;
  ushort* Wv_bf  = u11,       *Wwp_bf = u11 + WU;
  ushort* Wo_bf  = u10;

  // conv1: splits + P1/P2 weights
  {
    CvtArgs a{};
    a.d[0] = {query,  query_hi, query_lo, (int)(AU/4)};
    a.d[1] = {key_in, key_hi,   key_lo,   (int)(AU/4)};
    a.d[2] = {Whq,    Whq_hi,   Whq_lo,   (int)(WU/4)};
    a.d[3] = {Whk,    Whk_hi,   Whk_lo,   (int)(WU/4)};
    a.d[4] = {Wq,     Wq_bf,    nullptr,  (int)(WU/4)};
    a.d[5] = {Wk,     Wk_bf,    nullptr,  (int)(WU/4)};
    a.d[6] = {Wv,     Wv_bf,    nullptr,  (int)(WU/4)};
    a.d[7] = {Wwp,    Wwp_bf,   nullptr,  (int)(WU/4)};
    cvt_kernel<<<dim3(64, 8), 256, 0, stream>>>(a);
  }
  // P2: split GEMMs hq, hk
  {
    SplitArgs a{};
    a.s[0] = {query_hi, query_lo, Whq_hi, Whq_lo, bhq, hq_hi, hq_lo, SCALE_};
    a.s[1] = {key_hi,   key_lo,   Whk_hi, Whk_lo, bhk, hk_hi, hk_lo, 1.f};
    gemm_mfma_split<<<dim3(32, 16), 256, 0, stream>>>(a);
  }
  // conv2: value -> bf16 (reuses query_lo slot)
  {
    CvtArgs a{};
    a.d[0] = {value, value_bf, nullptr, (int)(AU/4)};
    cvt_kernel<<<dim3(64, 1), 256, 0, stream>>>(a);
  }
  // P1: plain GEMMs q, wp, k, v
  {
    PlainArgs a{};
    a.s[0] = {query_hi, Wq_bf,  bq,  q_bf,  nullptr, SCALE_, 0};
    a.s[1] = {query_hi, Wwp_bf, bwp, wp_bf, nullptr, 1.f,    1};
    a.s[2] = {key_hi,   Wk_bf,  bk,  k_bf,  nullptr, 1.f,    0};
    a.s[3] = {value_bf, Wv_bf,  bv,  v_out, nullptr, 1.f,    0};
    gemm_mfma_plain<<<dim3(64, 16), 256, 0, stream>>>(a);
  }
  vp_sigma<<<dim3(M_), dim3(64), 0, stream>>>(wp_bf, Wvp, bvp, sig);
  // conv3: Wo -> bf16 (reuses u10 after P1 consumed Wq/Wk)
  {
    CvtArgs a{};
    a.d[0] = {Wo, Wo_bf, nullptr, (int)(WU/4)};
    cvt_kernel<<<dim3(64, 1), 256, 0, stream>>>(a);
  }
  attn_mfma<<<dim3(T_/64, B_*H_), dim3(256), 0, stream>>>(
      q_bf, k_bf, v_out, hq_hi, hq_lo, hk_hi, hk_lo, sig, ctx_bf);
  // P3: output projection (fp32 out)
  {
    PlainArgs a{};
    a.s[0] = {ctx_bf, Wo_bf, bo, nullptr, (float*)d_out, 1.f, 0};
    gemm_mfma_plain<<<dim3(16, 16), 256, 0, stream>>>(a);
  }
}

// Round 4
// 146.100 us; speedup vs baseline: 9.0033x; 1.3369x over previous
//
#include <hip/hip_runtime.h>
#include <hip/hip_bf16.h>
#include <hip/hip_fp16.h>

#define T_ 1024
#define S_ 1024
#define B_ 2
#define H_ 16
#define D_ 64
#define E_ 1024
#define M_ (T_*B_)
#define SCALE_ 0.125f

typedef __attribute__((ext_vector_type(8))) short short8;
typedef __attribute__((ext_vector_type(8))) _Float16 half8;
typedef __attribute__((ext_vector_type(4))) float f32x4;

__device__ __forceinline__ ushort f2bf(float x) {
  unsigned u = __float_as_uint(x);
  unsigned r = (u + 0x7fffu + ((u >> 16) & 1u)) >> 16;
  return (ushort)r;
}
__device__ __forceinline__ float bf2f(ushort h) {
  return __uint_as_float(((unsigned)h) << 16);
}
__device__ __forceinline__ ushort f2h(float x) {
  __half h = __float2half(x);
  return *(ushort*)&h;
}
__device__ __forceinline__ void gld16(const void* g, void* l) {
  __builtin_amdgcn_global_load_lds(
      (const __attribute__((address_space(1))) void*)g,
      (__attribute__((address_space(3))) void*)l, 16, 0, 0);
}

// swizzled ushort index within a [64][64] (or [16][64]) tile
#define SWZ(r, col) ((r)*64 + ((col) ^ (((r)&7)<<3)))

// ---------------------------------------------------------------------------
// fp32 -> bf16 and/or fp16 conversion, multi-tensor
// ---------------------------------------------------------------------------
struct CvtDesc { const float* src; ushort* bf; ushort* h16; int n4; };
struct CvtArgs { CvtDesc d[10]; };

__global__ __launch_bounds__(256) void cvt_kernel(CvtArgs a) {
  const CvtDesc d = a.d[blockIdx.y];
  const int stride = gridDim.x * 256;
  for (int i = blockIdx.x*256 + threadIdx.x; i < d.n4; i += stride) {
    float4 v = ((const float4*)d.src)[i];
    float vals[4] = {v.x, v.y, v.z, v.w};
    if (d.bf) {
      ushort h[4];
      #pragma unroll
      for (int j = 0; j < 4; ++j) h[j] = f2bf(vals[j]);
      ((ushort4*)d.bf)[i] = make_ushort4(h[0],h[1],h[2],h[3]);
    }
    if (d.h16) {
      ushort h[4];
      #pragma unroll
      for (int j = 0; j < 4; ++j) h[j] = f2h(vals[j]);
      ((ushort4*)d.h16)[i] = make_ushort4(h[0],h[1],h[2],h[3]);
    }
  }
}

// ---------------------------------------------------------------------------
// MFMA GEMM: C_seg = act((A @ W^T + bias) * scale)
// FMT 0: bf16 in, bf16/f32 out.  FMT 1: fp16 in, fp16 out.
// Tile 128(M) x 64(N), BK=64, 4 waves, 16 n-blocks per segment.
// ---------------------------------------------------------------------------
struct SegP { const ushort* A; const ushort* W; const float* bias;
              ushort* outb; float* outf; float scale; int do_tanh; };
struct PlainArgs { SegP s[4]; };

template<int FMT>
__global__ __launch_bounds__(256) void gemm_mfma(PlainArgs args) {
  __shared__ ushort sA[128*64];
  __shared__ ushort sW[64*64];
  const int bx = blockIdx.x;
  const SegP sg = args.s[bx >> 4];
  const int n0 = (bx & 15) * 64;
  const int m0 = blockIdx.y * 128;
  const int tid = threadIdx.x, wv = tid >> 6, lane = tid & 63;
  const int c = lane & 15, g = lane >> 4;
  const int wr = wv >> 1, wc = wv & 1;
  const int l8 = lane >> 3, l7 = lane & 7;

  f32x4 acc[4][2] = {};
  for (int k0 = 0; k0 < 1024; k0 += 64) {
    #pragma unroll
    for (int i = 0; i < 4; ++i) {
      int row = wv*32 + i*8 + l8;
      gld16(sg.A + (size_t)(m0+row)*1024 + k0 + l7*8, &sA[(wv*32 + i*8)*64]);
    }
    #pragma unroll
    for (int i = 0; i < 2; ++i) {
      int row = wv*16 + i*8 + l8;
      gld16(sg.W + (size_t)(n0+row)*1024 + k0 + l7*8, &sW[(wv*16 + i*8)*64]);
    }
    __syncthreads();
    #pragma unroll
    for (int ks = 0; ks < 2; ++ks) {
      short8 af[4], wf[2];
      #pragma unroll
      for (int mi = 0; mi < 4; ++mi)
        af[mi] = *(const short8*)&sA[(wr*64 + mi*16 + c)*64 + ks*32 + g*8];
      #pragma unroll
      for (int ni = 0; ni < 2; ++ni)
        wf[ni] = *(const short8*)&sW[(wc*32 + ni*16 + c)*64 + ks*32 + g*8];
      #pragma unroll
      for (int mi = 0; mi < 4; ++mi)
        #pragma unroll
        for (int ni = 0; ni < 2; ++ni) {
          if (FMT == 0)
            acc[mi][ni] = __builtin_amdgcn_mfma_f32_16x16x32_bf16(
                af[mi], wf[ni], acc[mi][ni], 0, 0, 0);
          else
            acc[mi][ni] = __builtin_amdgcn_mfma_f32_16x16x32_f16(
                *(half8*)&af[mi], *(half8*)&wf[ni], acc[mi][ni], 0, 0, 0);
        }
    }
    __syncthreads();
  }
  #pragma unroll
  for (int ni = 0; ni < 2; ++ni) {
    int col = n0 + wc*32 + ni*16 + c;
    float bias = sg.bias[col];
    #pragma unroll
    for (int mi = 0; mi < 4; ++mi) {
      #pragma unroll
      for (int r = 0; r < 4; ++r) {
        int row = m0 + wr*64 + mi*16 + 4*g + r;
        float val = (acc[mi][ni][r] + bias) * sg.scale;
        if (FMT == 0 && sg.do_tanh) val = tanhf(val);
        if (FMT == 1)     sg.outb[(size_t)row*1024 + col] = f2h(val);
        else if (sg.outf) sg.outf[(size_t)row*1024 + col] = val;
        else              sg.outb[(size_t)row*1024 + col] = f2bf(val);
      }
    }
  }
}

// ---------------------------------------------------------------------------
// sigma[m] = 1 + sigmoid(sum_e wp_bf[m][e]*Wvp[e] + bvp), one wave per row
// ---------------------------------------------------------------------------
__global__ __launch_bounds__(64) void vp_sigma(const ushort* __restrict__ wp,
    const float* __restrict__ Wvp, const float* __restrict__ bvp,
    float* __restrict__ sigma) {
  const int m = blockIdx.x;
  const int lane = threadIdx.x;
  float acc = 0.f;
  #pragma unroll
  for (int it = 0; it < 2; ++it) {
    int e = lane*8 + it*512;
    short8 a = *(const short8*)&wp[(size_t)m*E_ + e];
    float4 w0 = *(const float4*)&Wvp[e];
    float4 w1 = *(const float4*)&Wvp[e+4];
    acc += bf2f((ushort)a[0])*w0.x + bf2f((ushort)a[1])*w0.y
         + bf2f((ushort)a[2])*w0.z + bf2f((ushort)a[3])*w0.w
         + bf2f((ushort)a[4])*w1.x + bf2f((ushort)a[5])*w1.y
         + bf2f((ushort)a[6])*w1.z + bf2f((ushort)a[7])*w1.w;
  }
  #pragma unroll
  for (int o = 32; o; o >>= 1) acc += __shfl_xor(acc, o);
  if (lane == 0) {
    float gg = acc + bvp[0];
    sigma[m] = 1.f + 1.f/(1.f + __expf(-gg));
  }
}

// ---------------------------------------------------------------------------
// MFMA flash attention with Gaussian bias.
// Pass1: align logits fp16 MFMA -> tile-max softmax -> mean.
// Pass2: content bf16 MFMA + gauss -> online softmax -> PV.
// All LDS tiles [64][64] linear + XOR swizzle (col ^ ((row&7)<<3)).
// K/HK staged via global_load_lds with pre-swizzled global source.
// ---------------------------------------------------------------------------
__global__ __launch_bounds__(256) void attn_mfma(
    const ushort* __restrict__ q_bf, const ushort* __restrict__ k_bf,
    const ushort* __restrict__ v_bf,
    const ushort* __restrict__ hq_h16, const ushort* __restrict__ hk_h16,
    const float* __restrict__ sigma, ushort* __restrict__ ctx) {
  __shared__ ushort sK[64*64];       // K or HK tile [s][d], swizzled
  __shared__ ushort sV[64*64];       // V^T tile [d][s], swizzled
  __shared__ ushort sP[4*16*64];     // per-wave P [q][s], swizzled

  const int bh = blockIdx.y;
  const int b = bh >> 4, h = bh & 15;
  const int t0 = blockIdx.x * 64;
  const int tid = threadIdx.x;
  const int wv = tid >> 6, lane = tid & 63;
  const int c = lane & 15, g = lane >> 4;
  const int qbase = t0 + wv * 16;

  const long rowstr = (long)B_ * E_;
  const long qoff = ((long)(qbase + c) * B_ + b) * E_ + h * 64;

  short8 qf[2];
  half8  hqf[2];
  #pragma unroll
  for (int cs = 0; cs < 2; ++cs) {
    qf[cs]  = *(const short8*)&q_bf[qoff + cs*32 + g*8];
    hqf[cs] = *(const half8*)&hq_h16[qoff + cs*32 + g*8];
  }

  // staging geometry (per wave: rows [wv*16, wv*16+16), 2 gld16)
  const int strow[2] = { wv*16 + (lane>>3), wv*16 + 8 + (lane>>3) };
  const int stchk[2] = { (lane&7) ^ (strow[0]&7), (lane&7) ^ (strow[1]&7) };

  // ------------------- pass 1: alignment softmax -> mean -------------------
  float M1 = -1e30f, den = 0.f, num = 0.f;
  for (int s0 = 0; s0 < S_; s0 += 64) {
    __syncthreads();
    #pragma unroll
    for (int it = 0; it < 2; ++it)
      gld16(hk_h16 + ((size_t)(s0 + strow[it]) * B_ + b) * E_ + h*64 + stchk[it]*8,
            &sK[(wv*16 + it*8)*64]);
    __syncthreads();

    f32x4 acc[4] = {};
    #pragma unroll
    for (int m = 0; m < 4; ++m)
      #pragma unroll
      for (int cs = 0; cs < 2; ++cs)
        acc[m] = __builtin_amdgcn_mfma_f32_16x16x32_f16(
            *(const half8*)&sK[SWZ(c + 16*m, cs*32 + g*8)], hqf[cs], acc[m], 0,0,0);

    float lmax = -1e30f;
    #pragma unroll
    for (int m = 0; m < 4; ++m)
      #pragma unroll
      for (int r = 0; r < 4; ++r) lmax = fmaxf(lmax, acc[m][r]);
    lmax = fmaxf(lmax, __shfl_xor(lmax, 16));
    lmax = fmaxf(lmax, __shfl_xor(lmax, 32));
    float dt = 0.f, nt = 0.f;
    #pragma unroll
    for (int m = 0; m < 4; ++m)
      #pragma unroll
      for (int r = 0; r < 4; ++r) {
        float e = __expf(acc[m][r] - lmax);
        dt += e;
        nt += e * (float)(s0 + 16*m + 4*g + r);
      }
    dt += __shfl_xor(dt, 16); dt += __shfl_xor(dt, 32);
    nt += __shfl_xor(nt, 16); nt += __shfl_xor(nt, 32);
    float Mn = fmaxf(M1, lmax);
    float c0 = __expf(M1 - Mn), c1 = __expf(lmax - Mn);
    den = den*c0 + dt*c1;
    num = num*c0 + nt*c1;
    M1 = Mn;
  }
  const float meanq = num / den;               // q = qbase + c (uniform in g)
  const float sg = sigma[(long)(qbase + c) * B_ + b];
  const float fct = -1.f / (2.f * sg * sg);

  // ------------------- pass 2: content softmax + PV -------------------------
  f32x4 accO[4] = {};                          // O[q=4g+r][d=16n+c]
  float Mq = -1e30f, denq = 0.f;
  for (int s0 = 0; s0 < S_; s0 += 64) {
    __syncthreads();
    #pragma unroll
    for (int it = 0; it < 2; ++it)             // stage K [s][d] via gld_lds
      gld16(k_bf + ((size_t)(s0 + strow[it]) * B_ + b) * E_ + h*64 + stchk[it]*8,
            &sK[(wv*16 + it*8)*64]);
    {                                          // stage V^T [d][s] (VGPR path)
      int s2 = (tid & 31) * 2, d0 = (tid >> 5) * 8;
      long off0 = ((long)(s0 + s2) * B_ + b) * E_ + h * 64 + d0;
      uint4 ra = *(const uint4*)&v_bf[off0];
      uint4 rb = *(const uint4*)&v_bf[off0 + rowstr];
      const ushort* pa = (const ushort*)&ra;
      const ushort* pb = (const ushort*)&rb;
      #pragma unroll
      for (int j = 0; j < 8; ++j)
        *(unsigned*)&sV[SWZ(d0 + j, s2)] = (unsigned)pa[j] | ((unsigned)pb[j] << 16);
    }
    __syncthreads();

    f32x4 accL[4] = {};
    #pragma unroll
    for (int m = 0; m < 4; ++m)
      #pragma unroll
      for (int cs = 0; cs < 2; ++cs)
        accL[m] = __builtin_amdgcn_mfma_f32_16x16x32_bf16(
            *(const short8*)&sK[SWZ(c + 16*m, cs*32 + g*8)], qf[cs], accL[m], 0,0,0);

    float lg[4][4];
    float lmax = -1e30f;
    #pragma unroll
    for (int m = 0; m < 4; ++m)
      #pragma unroll
      for (int r = 0; r < 4; ++r) {
        float sp = (float)(s0 + 16*m + 4*g + r);
        float dd = sp - meanq;
        float l = accL[m][r] + fct * dd * dd;
        lg[m][r] = l;
        lmax = fmaxf(lmax, l);
      }
    lmax = fmaxf(lmax, __shfl_xor(lmax, 16));
    lmax = fmaxf(lmax, __shfl_xor(lmax, 32));
    float Mnew = fmaxf(Mq, lmax);
    float c0 = __expf(Mq - Mnew);
    float psum = 0.f;
    ushort pb16[4][4];
    #pragma unroll
    for (int m = 0; m < 4; ++m)
      #pragma unroll
      for (int r = 0; r < 4; ++r) {
        float p = __expf(lg[m][r] - Mnew);
        psum += p;
        pb16[m][r] = f2bf(p);
      }
    denq = denq * c0 + psum;
    Mq = Mnew;
    #pragma unroll
    for (int m = 0; m < 4; ++m)
      *(ushort4*)&sP[wv*1024 + SWZ(c, 16*m + 4*g)] =
          make_ushort4(pb16[m][0], pb16[m][1], pb16[m][2], pb16[m][3]);

    float c0r[4];
    #pragma unroll
    for (int r = 0; r < 4; ++r) c0r[r] = __shfl(c0, 4*g + r);
    #pragma unroll
    for (int n = 0; n < 4; ++n)
      #pragma unroll
      for (int r = 0; r < 4; ++r) accO[n][r] *= c0r[r];

    #pragma unroll
    for (int n = 0; n < 4; ++n)
      #pragma unroll
      for (int cs = 0; cs < 2; ++cs)
        accO[n] = __builtin_amdgcn_mfma_f32_16x16x32_bf16(
            *(const short8*)&sP[wv*1024 + SWZ(c, cs*32 + 8*g)],
            *(const short8*)&sV[SWZ(c + 16*n, cs*32 + 8*g)],
            accO[n], 0,0,0);
  }

  denq += __shfl_xor(denq, 16);
  denq += __shfl_xor(denq, 32);
  float dinv[4];
  #pragma unroll
  for (int r = 0; r < 4; ++r) dinv[r] = 1.f / __shfl(denq, 4*g + r);

  #pragma unroll
  for (int r = 0; r < 4; ++r) {
    long row = ((long)(t0 + wv*16 + 4*g + r) * B_ + b) * E_ + h * 64;
    #pragma unroll
    for (int n = 0; n < 4; ++n)
      ctx[row + 16*n + c] = f2bf(accO[n][r] * dinv[r]);
  }
}

// ---------------------------------------------------------------------------
extern "C" void kernel_launch(void* const* d_in, const int* in_sizes, int n_in,
                              void* d_out, int out_size, void* d_ws, size_t ws_size,
                              hipStream_t stream) {
  const float* query  = (const float*)d_in[0];
  const float* key_in = (const float*)d_in[1];
  const float* value  = (const float*)d_in[2];
  const float* Wq  = (const float*)d_in[3];  const float* bq  = (const float*)d_in[4];
  const float* Wk  = (const float*)d_in[5];  const float* bk  = (const float*)d_in[6];
  const float* Wv  = (const float*)d_in[7];  const float* bv  = (const float*)d_in[8];
  const float* Whq = (const float*)d_in[9];  const float* bhq = (const float*)d_in[10];
  const float* Whk = (const float*)d_in[11]; const float* bhk = (const float*)d_in[12];
  const float* Wwp = (const float*)d_in[13]; const float* bwp = (const float*)d_in[14];
  const float* Wvp = (const float*)d_in[15]; const float* bvp = (const float*)d_in[16];
  const float* Wo  = (const float*)d_in[17]; const float* bo  = (const float*)d_in[18];

  const size_t AU = (size_t)M_ * E_;       // 2M elems -> 4MB @16bit
  const size_t WU = (size_t)E_ * E_;       // 1M elems -> 2MB @16bit
  char* p = (char*)d_ws;
  float*  sig       = (float*)p;  p += 16384;
  ushort* query_bf  = (ushort*)p; p += AU*2;
  ushort* key_bf    = (ushort*)p; p += AU*2;
  ushort* value_bf  = (ushort*)p; p += AU*2;
  ushort* query_h16 = (ushort*)p; p += AU*2;   // -> ctx_bf after P2
  ushort* key_h16   = (ushort*)p; p += AU*2;
  ushort* Whq_h16   = (ushort*)p; p += WU*2;   // -> wp_bf after P2 (w/ Whk)
  ushort* Whk_h16   = (ushort*)p; p += WU*2;
  ushort* Wq_bf     = (ushort*)p; p += WU*2;
  ushort* Wk_bf     = (ushort*)p; p += WU*2;
  ushort* Wv_bf     = (ushort*)p; p += WU*2;
  ushort* Wwp_bf    = (ushort*)p; p += WU*2;
  ushort* Wo_bf     = (ushort*)p; p += WU*2;
  ushort* hq_h16    = (ushort*)p; p += AU*2;
  ushort* hk_h16    = (ushort*)p; p += AU*2;
  ushort* q_bf      = (ushort*)p; p += AU*2;
  ushort* k_bf      = (ushort*)p; p += AU*2;
  ushort* v_out     = (ushort*)p; p += AU*2;
  ushort* ctx_bf    = query_h16;               // dead after P2
  ushort* wp_bf     = Whq_h16;                 // Whq+Whk region (4MB), dead after P2

  // conv: all precision conversions in one launch
  {
    CvtArgs a{};
    a.d[0] = {query,  query_bf, query_h16, (int)(AU/4)};
    a.d[1] = {key_in, key_bf,   key_h16,   (int)(AU/4)};
    a.d[2] = {value,  value_bf, nullptr,   (int)(AU/4)};
    a.d[3] = {Whq,    nullptr,  Whq_h16,   (int)(WU/4)};
    a.d[4] = {Whk,    nullptr,  Whk_h16,   (int)(WU/4)};
    a.d[5] = {Wq,     Wq_bf,    nullptr,   (int)(WU/4)};
    a.d[6] = {Wk,     Wk_bf,    nullptr,   (int)(WU/4)};
    a.d[7] = {Wv,     Wv_bf,    nullptr,   (int)(WU/4)};
    a.d[8] = {Wwp,    Wwp_bf,   nullptr,   (int)(WU/4)};
    a.d[9] = {Wo,     Wo_bf,    nullptr,   (int)(WU/4)};
    cvt_kernel<<<dim3(128, 10), 256, 0, stream>>>(a);
  }
  // P2: fp16 GEMMs hq, hk
  {
    PlainArgs a{};
    a.s[0] = {query_h16, Whq_h16, bhq, hq_h16, nullptr, SCALE_, 0};
    a.s[1] = {key_h16,   Whk_h16, bhk, hk_h16, nullptr, 1.f,    0};
    gemm_mfma<1><<<dim3(32, 16), 256, 0, stream>>>(a);
  }
  // P1: bf16 GEMMs q, wp, k, v
  {
    PlainArgs a{};
    a.s[0] = {query_bf, Wq_bf,  bq,  q_bf,  nullptr, SCALE_, 0};
    a.s[1] = {query_bf, Wwp_bf, bwp, wp_bf, nullptr, 1.f,    1};
    a.s[2] = {key_bf,   Wk_bf,  bk,  k_bf,  nullptr, 1.f,    0};
    a.s[3] = {value_bf, Wv_bf,  bv,  v_out, nullptr, 1.f,    0};
    gemm_mfma<0><<<dim3(64, 16), 256, 0, stream>>>(a);
  }
  vp_sigma<<<dim3(M_), dim3(64), 0, stream>>>(wp_bf, Wvp, bvp, sig);
  attn_mfma<<<dim3(T_/64, B_*H_), dim3(256), 0, stream>>>(
      q_bf, k_bf, v_out, hq_h16, hk_h16, sig, ctx_bf);
  // P3: output projection (fp32 out)
  {
    PlainArgs a{};
    a.s[0] = {ctx_bf, Wo_bf, bo, nullptr, (float*)d_out, 1.f, 0};
    gemm_mfma<0><<<dim3(16, 16), 256, 0, stream>>>(a);
  }
}